// Round 3
// baseline (948.819 us; speedup 1.0000x reference)
//
#include <hip/hip_runtime.h>
#include <hip/hip_bf16.h>

// MoE top-2: T=8192 tokens, D=1024, F=4096, E=8.
// Pipeline: fused transpose-cast -> router -> gather -> GEMM1(gelu) -> GEMM2(gated bf16 P) -> combine.

#define T_TOK 8192
#define DDIM  1024
#define FDIM  4096
#define NEXP  8
#define RTOT  (T_TOK * 2)      // total assigned rows (top-2, always exactly 2T)
#define RPAD  (RTOT + 128)     // slack so tile staging can over-read harmlessly

#define BM 128
#define BN 128
#define BK 64

typedef __bf16 bf16x8 __attribute__((ext_vector_type(8)));
typedef float  f32x4  __attribute__((ext_vector_type(4)));

__device__ __forceinline__ float gelu_tanh(float x) {
  // 0.5x(1+tanh(u)) == x * sigmoid(2u); u = sqrt(2/pi)(x + 0.044715 x^3)
  float x2 = x * x;
  float u = x * (0.7978845608028654f + 0.0356774081f * x2);
  return __fdividef(x, 1.f + __expf(-2.f * u));
}

__device__ __forceinline__ float b2f(unsigned short u) {
  return __uint_as_float(((unsigned)u) << 16);
}

#define GLOBAL_TO_LDS16(gp, lp)                                                   \
  __builtin_amdgcn_global_load_lds((const __attribute__((address_space(1))) void*)(gp), \
                                   (__attribute__((address_space(3))) void*)(lp), 16, 0, 0)

// ---------------- fused transpose+cast for w1 and w2 ----------------
// fp32 [E][Rr][Cc] -> bf16 [E][Cc][Rr]. 64x64 tiles. Phase 1: float4 loads, packed
// b32 LDS writes into transposed tile (stride 72 keeps b128 16B-alignment for all rows).
// Phase 2: ds_read_b128 + 16B global stores. Target: HBM-bound (~402 MB total).
__global__ __launch_bounds__(256) void transpose_cast_both(const float* __restrict__ w1,
                                                           const float* __restrict__ w2,
                                                           __hip_bfloat16* __restrict__ w1t,
                                                           __hip_bfloat16* __restrict__ w2t) {
  __shared__ __hip_bfloat16 tileT[64 * 72];  // tileT[c*72 + r] = in[r][c]
  int bid = blockIdx.x;
  const float* in; __hip_bfloat16* outp; int Rr, Cc;
  if (bid < NEXP * 1024) { in = w1; outp = w1t; Rr = DDIM; Cc = FDIM; }
  else { bid -= NEXP * 1024; in = w2; outp = w2t; Rr = FDIM; Cc = DDIM; }
  int tilesC = Cc >> 6;
  int per = (Rr >> 6) * tilesC;  // == 1024
  int e = bid / per, rem = bid % per;
  int tr = rem / tilesC, tc = rem % tilesC;
  const float* ip = in + (size_t)e * Rr * Cc + (size_t)(tr * 64) * Cc + tc * 64;
  __hip_bfloat16* op = outp + (size_t)e * Rr * Cc + (size_t)(tc * 64) * Rr + tr * 64;
  int tid = threadIdx.x;
  int cbase = (tid & 15) * 4;   // 4 consecutive columns
  int rbase = (tid >> 4) * 2;   // 2 consecutive rows (even), +32 per p
#pragma unroll
  for (int p = 0; p < 2; p++) {
    int r0 = rbase + p * 32;
    float4 va = *(const float4*)(ip + (size_t)r0 * Cc + cbase);
    float4 vb = *(const float4*)(ip + (size_t)(r0 + 1) * Cc + cbase);
    const float* fa = &va.x;
    const float* fb = &vb.x;
#pragma unroll
    for (int i = 0; i < 4; i++) {
      union { __hip_bfloat16 h[2]; unsigned u; } pk;
      pk.h[0] = __float2bfloat16(fa[i]);
      pk.h[1] = __float2bfloat16(fb[i]);
      *(unsigned*)(&tileT[(cbase + i) * 72 + r0]) = pk.u;  // r0 even: 4B-aligned
    }
  }
  __syncthreads();
  // phase 2: thread covers output row rr (= orig col), 16 elems starting at sb
  int rr = tid >> 2, sb = (tid & 3) * 16;
  const __hip_bfloat16* src = tileT + rr * 72 + sb;
  __hip_bfloat16* dst = op + (size_t)rr * Rr + sb;
  uint4 v0 = *(const uint4*)(src);
  uint4 v1 = *(const uint4*)(src + 8);
  *(uint4*)(dst) = v0;
  *(uint4*)(dst + 8) = v1;
}

// ---------------- router: logits -> top2 -> gates + slot assignment ----------------
__global__ __launch_bounds__(256) void router_kernel(const float* __restrict__ x,
                                                     const float* __restrict__ rw,
                                                     int* __restrict__ counts,
                                                     int* __restrict__ pair_e,
                                                     int* __restrict__ pair_slot,
                                                     float* __restrict__ pair_gate) {
  int lane = threadIdx.x & 63;
  int wid = threadIdx.x >> 6;
  int t = blockIdx.x * 4 + wid;  // one wave per token
  const float* xr = x + (size_t)t * DDIM;
  float acc[NEXP];
#pragma unroll
  for (int e = 0; e < NEXP; e++) acc[e] = 0.f;
  for (int d0 = lane * 4; d0 < DDIM; d0 += 256) {
    float4 xv = *(const float4*)(xr + d0);
    const float* r0 = rw + (size_t)d0 * NEXP;
#pragma unroll
    for (int e = 0; e < NEXP; e++)
      acc[e] += xv.x * r0[e] + xv.y * r0[NEXP + e] + xv.z * r0[2 * NEXP + e] + xv.w * r0[3 * NEXP + e];
  }
#pragma unroll
  for (int e = 0; e < NEXP; e++) {
#pragma unroll
    for (int m = 32; m > 0; m >>= 1) acc[e] += __shfl_xor(acc[e], m, 64);
  }
  if (lane == 0) {
    int e1 = 0; float l1 = acc[0];
    for (int e = 1; e < NEXP; e++) if (acc[e] > l1) { l1 = acc[e]; e1 = e; }
    int e2 = -1; float l2 = -1e30f;
    for (int e = 0; e < NEXP; e++) { if (e == e1) continue; if (acc[e] > l2) { l2 = acc[e]; e2 = e; } }
    // renormalized top-2 softmax == softmax over the two logits
    float g1 = 1.f / (1.f + __expf(l2 - l1));
    float g2 = 1.f - g1;
    int s1 = atomicAdd(&counts[e1], 1);
    int s2 = atomicAdd(&counts[e2], 1);
    pair_e[2 * t] = e1;     pair_slot[2 * t] = s1;     pair_gate[2 * t] = g1;
    pair_e[2 * t + 1] = e2; pair_slot[2 * t + 1] = s2; pair_gate[2 * t + 1] = g2;
  }
}

// ---------------- gather: x rows -> expert-compacted bf16 Xg ----------------
__global__ __launch_bounds__(256) void gather_kernel(const float* __restrict__ x,
                                                     const int* __restrict__ counts,
                                                     const int* __restrict__ pair_e,
                                                     const int* __restrict__ pair_slot,
                                                     const float* __restrict__ pair_gate,
                                                     __hip_bfloat16* __restrict__ Xg,
                                                     int* __restrict__ trow,
                                                     float* __restrict__ row_gate) {
  int p = blockIdx.x;
  int t = p >> 1;
  int e = pair_e[p];
  int base = 0;
#pragma unroll
  for (int i = 0; i < NEXP; i++) base += (i < e) ? counts[i] : 0;
  int row = base + pair_slot[p];
  const float* xr = x + (size_t)t * DDIM;
  __hip_bfloat16* dst = Xg + (size_t)row * DDIM;
  int i = threadIdx.x * 4;
  float4 v = *(const float4*)(xr + i);
  union { ushort4 u; __hip_bfloat16 h[4]; } o;
  o.h[0] = __float2bfloat16(v.x);
  o.h[1] = __float2bfloat16(v.y);
  o.h[2] = __float2bfloat16(v.z);
  o.h[3] = __float2bfloat16(v.w);
  *(ushort4*)(dst + i) = o.u;
  if (threadIdx.x == 0) { trow[p] = row; row_gate[row] = pair_gate[p]; }
}

// ---------------- tiled bf16 MFMA GEMM, per-expert row ranges ----------------
// A: bf16 [RPAD][K] (expert-compacted). Bw: bf16 [E][N][K].
// LDS XOR-swizzled: slot (r,c) holds global chunk (r, c^(r&7)) -> conflict-free frag reads.
// All LDS fragment offsets + global staging pointers hoisted out of the K-loop.
// EPI=0: Pout[row][N] = gelu(A@B) bf16 (H).  EPI=1: Pout[row][N] = gate*(A@B) bf16 (P).
template <int EPI>
__global__ __launch_bounds__(256) void moe_gemm(const __hip_bfloat16* __restrict__ A,
                                                const __hip_bfloat16* __restrict__ Bw,
                                                __hip_bfloat16* __restrict__ Pout,
                                                const int* __restrict__ counts,
                                                const float* __restrict__ row_gate,
                                                int K, int N) {
  const int MT = T_TOK / BM;  // worst-case m-tiles per expert
  const int NT = N / BN;
  int bid = blockIdx.x;
  int e = bid / (MT * NT);
  int rem = bid % (MT * NT);
  const int GM = 8;
  int width = GM * NT;
  int group = rem / width;
  int gm0 = group * GM;
  int gsize = (MT - gm0 < GM) ? (MT - gm0) : GM;
  int mt = gm0 + (rem % gsize);
  int nt = (rem % width) / gsize;

  int n_e = counts[e];
  if (mt * BM >= n_e) return;
  int row0 = 0;
  for (int i = 0; i < NEXP; i++) row0 += (i < e) ? counts[i] : 0;
  int m_start = row0 + mt * BM;
  int row_end = row0 + n_e;

  const __hip_bfloat16* Abase = A + (size_t)m_start * K;
  const __hip_bfloat16* Bbase = Bw + (size_t)e * N * K + (size_t)(nt * BN) * K;

  __shared__ alignas(16) __hip_bfloat16 As[BM * BK];
  __shared__ alignas(16) __hip_bfloat16 Bs[BN * BK];

  int tid = threadIdx.x;
  int lane = tid & 63, wid = tid >> 6;
  int wm = (wid >> 1) * 64, wn = (wid & 1) * 64;  // 2x2 wave grid, 64x64 each
  int lr = lane & 15;
  int kq8 = (lane >> 4);  // k-chunk base within 32-wide kk step

  // hoisted LDS fragment element-offsets (kt-invariant; 16 ints)
  int offA[4][2], offB[4][2];
#pragma unroll
  for (int i = 0; i < 4; i++) {
    int Ra = wm + i * 16 + lr;
    int Rb = wn + i * 16 + lr;
#pragma unroll
    for (int h = 0; h < 2; h++) {
      int kc = kq8 + h * 4;
      offA[i][h] = Ra * BK + ((kc ^ (Ra & 7)) * 8);
      offB[i][h] = Rb * BK + ((kc ^ (Rb & 7)) * 8);
    }
  }
  // hoisted global staging pointers (induction += BK per iter)
  const __hip_bfloat16* ga[4];
  const __hip_bfloat16* gb[4];
#pragma unroll
  for (int i = 0; i < 4; i++) {
    int q = i * 256 + tid;
    int r = q >> 3, c = (q & 7) ^ (r & 7);
    ga[i] = Abase + (size_t)r * K + c * 8;
    gb[i] = Bbase + (size_t)r * K + c * 8;
  }

  f32x4 acc[4][4];
#pragma unroll
  for (int i = 0; i < 4; i++)
#pragma unroll
    for (int j = 0; j < 4; j++)
#pragma unroll
      for (int r = 0; r < 4; r++) acc[i][j][r] = 0.f;

  for (int kt = 0; kt < K; kt += BK) {
#pragma unroll
    for (int i = 0; i < 4; i++) GLOBAL_TO_LDS16(ga[i], As + (size_t)(i * 256 + wid * 64) * 8);
#pragma unroll
    for (int i = 0; i < 4; i++) GLOBAL_TO_LDS16(gb[i], Bs + (size_t)(i * 256 + wid * 64) * 8);
#pragma unroll
    for (int i = 0; i < 4; i++) { ga[i] += BK; gb[i] += BK; }
    __syncthreads();
#pragma unroll
    for (int h = 0; h < 2; h++) {
      bf16x8 af[4], bfr[4];
#pragma unroll
      for (int i = 0; i < 4; i++) af[i] = *(const bf16x8*)(As + offA[i][h]);
#pragma unroll
      for (int j = 0; j < 4; j++) bfr[j] = *(const bf16x8*)(Bs + offB[j][h]);
#pragma unroll
      for (int i = 0; i < 4; i++)
#pragma unroll
        for (int j = 0; j < 4; j++)
          acc[i][j] = __builtin_amdgcn_mfma_f32_16x16x32_bf16(af[i], bfr[j], acc[i][j], 0, 0, 0);
    }
    __syncthreads();
  }

  // epilogue; C/D layout: col = lane&15, row = (lane>>4)*4 + reg  [m89-verified]
  int quad = (lane >> 4) * 4;
#pragma unroll
  for (int i = 0; i < 4; i++) {
#pragma unroll
    for (int r = 0; r < 4; r++) {
      int grow = m_start + wm + i * 16 + quad + r;
      if (grow < row_end) {
        __hip_bfloat16* pp = Pout + (size_t)grow * N + nt * BN + wn + lr;
        if (EPI == 0) {
#pragma unroll
          for (int j = 0; j < 4; j++)
            pp[j * 16] = __float2bfloat16(gelu_tanh(acc[i][j][r]));
        } else {
          float g = row_gate[grow];
#pragma unroll
          for (int j = 0; j < 4; j++)
            pp[j * 16] = __float2bfloat16(g * acc[i][j][r]);
        }
      }
    }
  }
}

// ---------------- combine: out[t] = P[row1] + P[row2] (gates pre-applied, bf16 P) ----------------
__global__ __launch_bounds__(256) void combine_kernel(const __hip_bfloat16* __restrict__ P,
                                                      const int* __restrict__ trow,
                                                      float* __restrict__ out) {
  int t = blockIdx.x;
  int r1 = trow[2 * t], r2 = trow[2 * t + 1];
  int d = threadIdx.x * 4;
  ushort4 a = *(const ushort4*)(P + (size_t)r1 * DDIM + d);
  ushort4 b = *(const ushort4*)(P + (size_t)r2 * DDIM + d);
  float4 o;
  o.x = b2f(a.x) + b2f(b.x);
  o.y = b2f(a.y) + b2f(b.y);
  o.z = b2f(a.z) + b2f(b.z);
  o.w = b2f(a.w) + b2f(b.w);
  *(float4*)(out + (size_t)t * DDIM + d) = o;
}

extern "C" void kernel_launch(void* const* d_in, const int* in_sizes, int n_in,
                              void* d_out, int out_size, void* d_ws, size_t ws_size,
                              hipStream_t stream) {
  (void)in_sizes; (void)n_in; (void)out_size; (void)ws_size;
  const float* x  = (const float*)d_in[0];
  const float* rw = (const float*)d_in[1];
  const float* w1 = (const float*)d_in[2];
  const float* w2 = (const float*)d_in[3];
  float* out = (float*)d_out;

  char* ws = (char*)d_ws;
  size_t off = 0;
  auto alloc = [&](size_t bytes) -> char* {
    off = (off + 255) & ~(size_t)255;
    char* p = ws + off;
    off += bytes;
    return p;
  };
  int*   counts    = (int*)alloc(NEXP * 4);
  int*   pair_e    = (int*)alloc((size_t)RTOT * 4);
  int*   pair_slot = (int*)alloc((size_t)RTOT * 4);
  float* pair_gate = (float*)alloc((size_t)RTOT * 4);
  int*   trow      = (int*)alloc((size_t)RTOT * 4);
  float* row_gate  = (float*)alloc((size_t)RTOT * 4);
  __hip_bfloat16* Xg  = (__hip_bfloat16*)alloc((size_t)RPAD * DDIM * 2);
  __hip_bfloat16* w1t = (__hip_bfloat16*)alloc((size_t)NEXP * DDIM * FDIM * 2);
  __hip_bfloat16* w2t = (__hip_bfloat16*)alloc((size_t)NEXP * DDIM * FDIM * 2);
  __hip_bfloat16* H   = (__hip_bfloat16*)alloc((size_t)RPAD * FDIM * 2);
  // P aliases w1t (dead after GEMM1): bf16 [RPAD][DDIM] = 33.8 MB < 67 MB.
  __hip_bfloat16* P = w1t;

  hipMemsetAsync(counts, 0, NEXP * 4, stream);

  transpose_cast_both<<<2 * NEXP * 1024, 256, 0, stream>>>(w1, w2, w1t, w2t);
  router_kernel<<<T_TOK / 4, 256, 0, stream>>>(x, rw, counts, pair_e, pair_slot, pair_gate);
  gather_kernel<<<RTOT, 256, 0, stream>>>(x, counts, pair_e, pair_slot, pair_gate, Xg, trow, row_gate);

  moe_gemm<0><<<NEXP * (T_TOK / BM) * (FDIM / BN), 256, 0, stream>>>(
      Xg, w1t, H, counts, nullptr, DDIM, FDIM);
  moe_gemm<1><<<NEXP * (T_TOK / BM) * (DDIM / BN), 256, 0, stream>>>(
      H, w2t, P, counts, row_gate, FDIM, DDIM);
  combine_kernel<<<T_TOK, 256, 0, stream>>>(P, trow, out);
}